// Round 9
// baseline (97.004 us; speedup 1.0000x reference)
//
#include <hip/hip_runtime.h>

// DistNet: out[n] = sigmoid((min_p ||x_n - p||^2 + alpha) / beta)
// beta = softplus(beta_raw), alpha = -beta*ln(1000)
// x: [65536,128] f32, points: [2048,128] f32, beta_raw: [1] f32, out: [65536] f32
//
// R15: MEASUREMENT ROUND. Main has never appeared in rocprof top-5 (every
// dispatch sits just under the 43us poison fills) -> 5 rounds of blind
// inference. Fix: exploit idempotence of max -- each wave covers 96 tiles
// instead of 64 (half 0: tiles 0..95, half 1: 32..127; union = 0..127,
// overlap double-counted harmlessly -> output bitwise identical). Dispatch
// grows to ~45-50us > fills -> main becomes top-5 WITH counters
// (MfmaUtil/VALUBusy/Occupancy/FETCH/LDS-conflict). Also a scaling probe:
// work x1.5 -- if dur scales ~1.5x the loop is throughput-bound, if <1.3x
// it's latency-bound. Kernel otherwise byte-for-byte R14 (wall 92.3, best;
// m ~= 32 vs ~13 floor).

#define NROWS 65536
#define NPTS  2048
#define DIMS  128
#define LOG1000F 6.9077542789816375f

typedef __attribute__((ext_vector_type(8))) int i32x8;
typedef __attribute__((ext_vector_type(4))) float f32x4;

union AFrag { int d[8]; i32x8 v; };
union BFrag { uint4 u4[2]; i32x8 v; };

// --- pre-kernel: points f32 -> fp8 e4m3, PRE-SWIZZLED fragment order --------
// 16B unit u = (T*2+c)*64 + q*16 + m  holds point p = T*16+m, features
// k in [q*32+c*16, q*32+c*16+16). Main kernel B-load for tile T is then
// unit[(T*2+c)*64 + lane], i.e. two contiguous 1KB dwordx4 loads.
// Also writes ||p||^2.
__global__ __launch_bounds__(256) void prep_points_kernel(
    const float* __restrict__ pts, unsigned char* __restrict__ ptsf8,
    float* __restrict__ pnorm)
{
    int tid  = threadIdx.x;
    int lane = tid & 63;
    int w    = tid >> 6;
    int pt   = blockIdx.x * 4 + w;            // one wave per point
    const float2 v = *reinterpret_cast<const float2*>(
        pts + (size_t)pt * DIMS + lane * 2);  // features 2*lane, 2*lane+1
    int pk = __builtin_amdgcn_cvt_pk_fp8_f32(v.x, v.y, 0, false);
    int T  = pt >> 4, pm = pt & 15;
    int q  = lane >> 4;                       // (2*lane)>>5
    int c  = (lane >> 3) & 1;                 // ((2*lane)>>4)&1
    int j  = (lane & 7) * 2;                  // (2*lane)&15
    size_t dst = (size_t)((T * 2 + c) * 64 + q * 16 + pm) * 16 + j;
    *reinterpret_cast<unsigned short*>(ptsf8 + dst) =
        (unsigned short)(pk & 0xFFFF);
    float ss = v.x * v.x + v.y * v.y;
    ss += __shfl_xor(ss, 1, 64);
    ss += __shfl_xor(ss, 2, 64);
    ss += __shfl_xor(ss, 4, 64);
    ss += __shfl_xor(ss, 8, 64);
    ss += __shfl_xor(ss, 16, 64);
    ss += __shfl_xor(ss, 32, 64);
    if (lane == 0) pnorm[pt] = ss;
}

// --- main kernel ------------------------------------------------------------
// grid: NROWS/128 = 512 blocks x 256 threads (4 waves, 2 per CU).
// Preamble: wave w converts row-tiles {2w, 2w+1} (its unique 32 rows ->
// x read exactly once), publishes fragments via LDS. Main loop: wave pair
// (pairw) owns 64 rows; half h covers tiles [h*32, h*32+96) -- 96 tiles,
// union over halves = all 128, overlap harmless (max idempotent).
__global__ __launch_bounds__(256, 2) void distnet_main_kernel(
    const float* __restrict__ x, const unsigned char* __restrict__ ptsf8,
    const float* __restrict__ pnorm, const float* __restrict__ beta_raw,
    float* __restrict__ out)
{
    __shared__ __align__(16) float s_pn[NPTS];   // 8 KB: -0.5*||p||^2
    __shared__ __align__(16) int s_af[8][64][8]; // 16 KB: A-frags, 8 row-tiles
    __shared__ float s_red[2][128];              // per-half partial max
    __shared__ float s_xn[128];                  // ||x||^2 per block row

    int tid = threadIdx.x;
    // stage -0.5*||p||^2 (MFMA C-input form) into LDS
    {
        const float4* p4 = reinterpret_cast<const float4*>(pnorm);
        float4* d4 = reinterpret_cast<float4*>(s_pn);
        float4 a = p4[tid], b = p4[tid + 256];
        d4[tid]       = make_float4(-.5f*a.x, -.5f*a.y, -.5f*a.z, -.5f*a.w);
        d4[tid + 256] = make_float4(-.5f*b.x, -.5f*b.y, -.5f*b.z, -.5f*b.w);
    }

    int wid   = tid >> 6, lane = tid & 63;
    int m     = lane & 15, q = lane >> 4;
    int pairw = wid >> 1, half = wid & 1;
    int rbase0 = blockIdx.x * 128;

    // Preamble: wave wid converts row-tiles {2*wid, 2*wid+1} only (x 1x).
    // Lane holds A[m][q*32+j] of each tile; publish to LDS for all waves.
#pragma unroll
    for (int i = 0; i < 2; ++i) {
        int lt = wid * 2 + i;                       // row-tile 0..7 in block
        const float* xp = x + (size_t)(rbase0 + lt * 16 + m) * DIMS + q * 32;
        AFrag af;
        float s = 0.f;
#pragma unroll
        for (int d = 0; d < 8; ++d) {
            float4 v = *reinterpret_cast<const float4*>(xp + d * 4);
            int w0 = __builtin_amdgcn_cvt_pk_fp8_f32(v.x, v.y, 0, false);
            w0 = __builtin_amdgcn_cvt_pk_fp8_f32(v.z, v.w, w0, true);
            af.d[d] = w0;
            s += v.x * v.x + v.y * v.y + v.z * v.z + v.w * v.w;
        }
        s += __shfl_xor(s, 16, 64);
        s += __shfl_xor(s, 32, 64);
        if (q == 0) s_xn[lt * 16 + m] = s;          // rows lt*16 + 0..15
        *reinterpret_cast<i32x8*>(&s_af[lt][lane][0]) = af.v;
    }
    __syncthreads();   // s_pn + s_xn + s_af visible; only barrier before epi

    // Read back this wave's 4 row-tiles (pair's 64 rows) from LDS.
    AFrag afrag[4];
#pragma unroll
    for (int t = 0; t < 4; ++t)
        afrag[t].v = *reinterpret_cast<const i32x8*>(&s_af[pairw * 4 + t][lane][0]);

    // runmax tracks max_p (x.p - ||p||^2/2); d2 = ||x||^2 - 2*max at the end.
    float runmax[4][4];
#pragma unroll
    for (int t = 0; t < 4; ++t)
#pragma unroll
        for (int r = 0; r < 4; ++r) runmax[t][r] = -1e30f;

    const uint4* bsw = reinterpret_cast<const uint4*>(ptsf8);
    const int T0 = half * 32;      // 96-tile window: h=0 -> 0..95, h=1 -> 32..127

    BFrag bA, bB, bC, bD;
    float pnA, pnB, pnC, pnD;

#define LOADT(gT, buf, pnh) do {                       \
        buf.u4[0] = bsw[(gT) * 128 + lane];            \
        buf.u4[1] = bsw[(gT) * 128 + 64 + lane];       \
        pnh = s_pn[(gT) * 16 + m];                     \
    } while (0)

    auto compute = [&](const BFrag& buf, float pnh) {
#pragma unroll
        for (int t = 0; t < 4; ++t) {
            f32x4 acc = {pnh, pnh, pnh, pnh};   // C = -||p||^2/2 broadcast
            acc = __builtin_amdgcn_mfma_scale_f32_16x16x128_f8f6f4(
                afrag[t].v, buf.v, acc, 0, 0, 0, 0x7F7F7F7F, 0, 0x7F7F7F7F);
#pragma unroll
            for (int r = 0; r < 4; ++r)
                runmax[t][r] = fmaxf(runmax[t][r], acc[r]);
        }
    };

    // depth-4 register prefetch; steady loop branch-free and NOT unrolled
    // (R9 lesson: full unroll -> live-range blowup -> spill).
    LOADT(T0 + 0, bA, pnA);
    LOADT(T0 + 1, bB, pnB);
    LOADT(T0 + 2, bC, pnC);
    LOADT(T0 + 3, bD, pnD);
#pragma unroll 1
    for (int T = 0; T < 92; T += 4) {        // 96 tiles: 23 groups + epilogue
        compute(bA, pnA);
        LOADT(T0 + T + 4, bA, pnA);
        compute(bB, pnB);
        LOADT(T0 + T + 5, bB, pnB);
        compute(bC, pnC);
        LOADT(T0 + T + 6, bC, pnC);
        compute(bD, pnD);
        LOADT(T0 + T + 7, bD, pnD);
    }
    compute(bA, pnA);
    compute(bB, pnB);
    compute(bC, pnC);
    compute(bD, pnD);
#undef LOADT

    // C/D layout: col = m (point), row_local = q*4 + r (x-row).
    // Max-reduce over the 16 cols, store per-half partial to LDS.
#pragma unroll
    for (int t = 0; t < 4; ++t) {
#pragma unroll
        for (int r = 0; r < 4; ++r) {
            float v = runmax[t][r];
            v = fmaxf(v, __shfl_xor(v, 1, 64));
            v = fmaxf(v, __shfl_xor(v, 2, 64));
            v = fmaxf(v, __shfl_xor(v, 4, 64));
            v = fmaxf(v, __shfl_xor(v, 8, 64));
            if (m == 0)
                s_red[half][pairw * 64 + t * 16 + q * 4 + r] = v;
        }
    }
    __syncthreads();

    if (tid < 128) {
        float vmax  = fmaxf(s_red[0][tid], s_red[1][tid]);
        float d2    = fmaxf(fmaf(-2.f, vmax, s_xn[tid]), 0.f);
        float br    = beta_raw[0];
        float beta  = log1pf(expf(br));
        float alpha = -beta * LOG1000F;
        float z     = (d2 + alpha) / beta;
        out[(size_t)blockIdx.x * 128 + tid] = 1.f / (1.f + expf(-z));
    }
}

extern "C" void kernel_launch(void* const* d_in, const int* in_sizes, int n_in,
                              void* d_out, int out_size, void* d_ws, size_t ws_size,
                              hipStream_t stream) {
    const float* x        = (const float*)d_in[0];
    const float* pts      = (const float*)d_in[1];
    const float* beta_raw = (const float*)d_in[2];
    float* out            = (float*)d_out;

    unsigned char* ptsf8 = (unsigned char*)d_ws;                    // 256 KB
    float* pnorm = (float*)((char*)d_ws + (size_t)NPTS * DIMS);     // 8 KB

    prep_points_kernel<<<NPTS / 4, 256, 0, stream>>>(pts, ptsf8, pnorm);
    distnet_main_kernel<<<NROWS / 128, 256, 0, stream>>>(x, ptsf8, pnorm,
                                                         beta_raw, out);
}

// Round 10
// 94.467 us; speedup vs baseline: 1.0269x; 1.0269x over previous
//
#include <hip/hip_runtime.h>

// DistNet: out[n] = sigmoid((min_p ||x_n - p||^2 + alpha) / beta)
// beta = softplus(beta_raw), alpha = -beta*ln(1000)
// x: [65536,128] f32, points: [2048,128] f32, beta_raw: [1] f32, out: [65536] f32
//
// R16: R15's scaling probe showed the B-loop runs at ~85% of its throughput
// floor (marginal cost 4.7us for +50% work = the MFMA+L2 floor). Main's ~32us
// = x-HBM preamble ~9.5 (R12 double-launch: warm-x run is ~22.5) + loop ~9.4
// + ~13 fixed latency (prologue/tail/barrier) -- all latency-shaped, at only
// 2 waves/SIMD (grid-limited). R16 doubles TLP cleanly: 512 blocks x 512 thr
// (4096 waves = 4/SIMD at ~120 VGPR), SAME 128-row block economy (B stays
// 134 MB L2), x read 1x. 8 waves = 2 rowgroups x 4 tile-quarters; each wave
// converts one row-tile and shares via LDS (R14 mechanism); per-wave loop is
// the proven depth-4/unroll-1 body over 32 tiles. B-prologue issues before
// the barrier (A-independent). launch_bounds(512,2) keeps the 256-reg
// budget: no forced-spill cliff (R8 lesson), graceful 3/SIMD if VGPR>128.

#define NROWS 65536
#define NPTS  2048
#define DIMS  128
#define LOG1000F 6.9077542789816375f

typedef __attribute__((ext_vector_type(8))) int i32x8;
typedef __attribute__((ext_vector_type(4))) float f32x4;

union AFrag { int d[8]; i32x8 v; };
union BFrag { uint4 u4[2]; i32x8 v; };

// --- pre-kernel: points f32 -> fp8 e4m3, PRE-SWIZZLED fragment order --------
// 16B unit u = (T*2+c)*64 + q*16 + m  holds point p = T*16+m, features
// k in [q*32+c*16, q*32+c*16+16). Main kernel B-load for tile T is then
// unit[(T*2+c)*64 + lane], i.e. two contiguous 1KB dwordx4 loads.
// Also writes ||p||^2.
__global__ __launch_bounds__(256) void prep_points_kernel(
    const float* __restrict__ pts, unsigned char* __restrict__ ptsf8,
    float* __restrict__ pnorm)
{
    int tid  = threadIdx.x;
    int lane = tid & 63;
    int w    = tid >> 6;
    int pt   = blockIdx.x * 4 + w;            // one wave per point
    const float2 v = *reinterpret_cast<const float2*>(
        pts + (size_t)pt * DIMS + lane * 2);  // features 2*lane, 2*lane+1
    int pk = __builtin_amdgcn_cvt_pk_fp8_f32(v.x, v.y, 0, false);
    int T  = pt >> 4, pm = pt & 15;
    int q  = lane >> 4;                       // (2*lane)>>5
    int c  = (lane >> 3) & 1;                 // ((2*lane)>>4)&1
    int j  = (lane & 7) * 2;                  // (2*lane)&15
    size_t dst = (size_t)((T * 2 + c) * 64 + q * 16 + pm) * 16 + j;
    *reinterpret_cast<unsigned short*>(ptsf8 + dst) =
        (unsigned short)(pk & 0xFFFF);
    float ss = v.x * v.x + v.y * v.y;
    ss += __shfl_xor(ss, 1, 64);
    ss += __shfl_xor(ss, 2, 64);
    ss += __shfl_xor(ss, 4, 64);
    ss += __shfl_xor(ss, 8, 64);
    ss += __shfl_xor(ss, 16, 64);
    ss += __shfl_xor(ss, 32, 64);
    if (lane == 0) pnorm[pt] = ss;
}

// --- main kernel ------------------------------------------------------------
// grid: NROWS/128 = 512 blocks x 512 threads (8 waves; ~120 VGPR -> 4
// waves/SIMD across 2 blocks/CU). Block owns 128 rows = 8 row-tiles.
// Preamble: wave w converts row-tile w only (x read exactly once),
// publishes fragments + ||x||^2 via LDS. Main loop: wave (g = wid>>2,
// c = wid&3) computes rowgroup g's 64 rows x point-tiles [c*32, c*32+32).
// No barriers in the main loop; 4-way LDS max-combine at the end.
__global__ __launch_bounds__(512, 2) void distnet_main_kernel(
    const float* __restrict__ x, const unsigned char* __restrict__ ptsf8,
    const float* __restrict__ pnorm, const float* __restrict__ beta_raw,
    float* __restrict__ out)
{
    __shared__ __align__(16) float s_pn[NPTS];   // 8 KB: -0.5*||p||^2
    __shared__ __align__(16) int s_af[8][64][8]; // 16 KB: A-frags, 8 row-tiles
    __shared__ float s_red[4][128];              // 2 KB: per-quarter partials
    __shared__ float s_xn[128];                  // ||x||^2 per block row

    int tid = threadIdx.x;
    // stage -0.5*||p||^2 (MFMA C-input form): 512 thr x 1 float4 = 2048
    {
        const float4* p4 = reinterpret_cast<const float4*>(pnorm);
        float4 a = p4[tid];
        reinterpret_cast<float4*>(s_pn)[tid] =
            make_float4(-.5f*a.x, -.5f*a.y, -.5f*a.z, -.5f*a.w);
    }

    int wid  = tid >> 6, lane = tid & 63;
    int m    = lane & 15, q = lane >> 4;
    int g    = wid >> 2, c = wid & 3;     // rowgroup (64 rows), tile-quarter
    int rbase0 = blockIdx.x * 128;

    // Preamble: wave wid converts row-tile wid only (16 rows; x 1x).
    // Lane holds A[m][q*32+j]; publish to LDS for all waves.
    {
        int lt = wid;                               // row-tile 0..7 in block
        const float* xp = x + (size_t)(rbase0 + lt * 16 + m) * DIMS + q * 32;
        AFrag af;
        float s = 0.f;
#pragma unroll
        for (int d = 0; d < 8; ++d) {
            float4 v = *reinterpret_cast<const float4*>(xp + d * 4);
            int w0 = __builtin_amdgcn_cvt_pk_fp8_f32(v.x, v.y, 0, false);
            w0 = __builtin_amdgcn_cvt_pk_fp8_f32(v.z, v.w, w0, true);
            af.d[d] = w0;
            s += v.x * v.x + v.y * v.y + v.z * v.z + v.w * v.w;
        }
        s += __shfl_xor(s, 16, 64);
        s += __shfl_xor(s, 32, 64);
        if (q == 0) s_xn[lt * 16 + m] = s;          // rows lt*16 + 0..15
        *reinterpret_cast<i32x8*>(&s_af[lt][lane][0]) = af.v;
    }

    // B prologue: issue the first 4 tile loads BEFORE the barrier
    // (A-independent global loads overlap the barrier wait).
    const uint4* bsw = reinterpret_cast<const uint4*>(ptsf8);
    const int T0 = c * 32;           // this wave's 32-tile quarter
    BFrag bA, bB, bC, bD;
    bA.u4[0] = bsw[(T0 + 0) * 128 + lane];
    bA.u4[1] = bsw[(T0 + 0) * 128 + 64 + lane];
    bB.u4[0] = bsw[(T0 + 1) * 128 + lane];
    bB.u4[1] = bsw[(T0 + 1) * 128 + 64 + lane];
    bC.u4[0] = bsw[(T0 + 2) * 128 + lane];
    bC.u4[1] = bsw[(T0 + 2) * 128 + 64 + lane];
    bD.u4[0] = bsw[(T0 + 3) * 128 + lane];
    bD.u4[1] = bsw[(T0 + 3) * 128 + 64 + lane];

    __syncthreads();   // s_pn + s_xn + s_af visible; only barrier before epi

    // Read back rowgroup g's 4 row-tiles (64 rows) from LDS.
    AFrag afrag[4];
#pragma unroll
    for (int t = 0; t < 4; ++t)
        afrag[t].v = *reinterpret_cast<const i32x8*>(&s_af[g * 4 + t][lane][0]);

    float pnA = s_pn[(T0 + 0) * 16 + m];
    float pnB = s_pn[(T0 + 1) * 16 + m];
    float pnC = s_pn[(T0 + 2) * 16 + m];
    float pnD = s_pn[(T0 + 3) * 16 + m];

    // runmax tracks max_p (x.p - ||p||^2/2); d2 = ||x||^2 - 2*max at the end.
    float runmax[4][4];
#pragma unroll
    for (int t = 0; t < 4; ++t)
#pragma unroll
        for (int r = 0; r < 4; ++r) runmax[t][r] = -1e30f;

#define LOADT(gT, buf, pnh) do {                       \
        buf.u4[0] = bsw[(gT) * 128 + lane];            \
        buf.u4[1] = bsw[(gT) * 128 + 64 + lane];       \
        pnh = s_pn[(gT) * 16 + m];                     \
    } while (0)

    auto compute = [&](const BFrag& buf, float pnh) {
#pragma unroll
        for (int t = 0; t < 4; ++t) {
            f32x4 acc = {pnh, pnh, pnh, pnh};   // C = -||p||^2/2 broadcast
            acc = __builtin_amdgcn_mfma_scale_f32_16x16x128_f8f6f4(
                afrag[t].v, buf.v, acc, 0, 0, 0, 0x7F7F7F7F, 0, 0x7F7F7F7F);
#pragma unroll
            for (int r = 0; r < 4; ++r)
                runmax[t][r] = fmaxf(runmax[t][r], acc[r]);
        }
    };

    // depth-4 register prefetch; steady loop branch-free and NOT unrolled
    // (R9 lesson: full unroll -> live-range blowup -> spill).
#pragma unroll 1
    for (int T = 0; T < 28; T += 4) {
        compute(bA, pnA);
        LOADT(T0 + T + 4, bA, pnA);
        compute(bB, pnB);
        LOADT(T0 + T + 5, bB, pnB);
        compute(bC, pnC);
        LOADT(T0 + T + 6, bC, pnC);
        compute(bD, pnD);
        LOADT(T0 + T + 7, bD, pnD);
    }
    compute(bA, pnA);
    compute(bB, pnB);
    compute(bC, pnC);
    compute(bD, pnD);
#undef LOADT

    // C/D layout: col = m (point), row_local = q*4 + r (x-row).
    // Max-reduce over the 16 cols, store per-quarter partial to LDS.
#pragma unroll
    for (int t = 0; t < 4; ++t) {
#pragma unroll
        for (int r = 0; r < 4; ++r) {
            float v = runmax[t][r];
            v = fmaxf(v, __shfl_xor(v, 1, 64));
            v = fmaxf(v, __shfl_xor(v, 2, 64));
            v = fmaxf(v, __shfl_xor(v, 4, 64));
            v = fmaxf(v, __shfl_xor(v, 8, 64));
            if (m == 0)
                s_red[c][g * 64 + t * 16 + q * 4 + r] = v;
        }
    }
    __syncthreads();

    if (tid < 128) {
        float vmax  = fmaxf(fmaxf(s_red[0][tid], s_red[1][tid]),
                            fmaxf(s_red[2][tid], s_red[3][tid]));
        float d2    = fmaxf(fmaf(-2.f, vmax, s_xn[tid]), 0.f);
        float br    = beta_raw[0];
        float beta  = log1pf(expf(br));
        float alpha = -beta * LOG1000F;
        float z     = (d2 + alpha) / beta;
        out[(size_t)blockIdx.x * 128 + tid] = 1.f / (1.f + expf(-z));
    }
}

extern "C" void kernel_launch(void* const* d_in, const int* in_sizes, int n_in,
                              void* d_out, int out_size, void* d_ws, size_t ws_size,
                              hipStream_t stream) {
    const float* x        = (const float*)d_in[0];
    const float* pts      = (const float*)d_in[1];
    const float* beta_raw = (const float*)d_in[2];
    float* out            = (float*)d_out;

    unsigned char* ptsf8 = (unsigned char*)d_ws;                    // 256 KB
    float* pnorm = (float*)((char*)d_ws + (size_t)NPTS * DIMS);     // 8 KB

    prep_points_kernel<<<NPTS / 4, 256, 0, stream>>>(pts, ptsf8, pnorm);
    distnet_main_kernel<<<NROWS / 128, 512, 0, stream>>>(x, ptsf8, pnorm,
                                                         beta_raw, out);
}

// Round 12
// 91.901 us; speedup vs baseline: 1.0555x; 1.0279x over previous
//
#include <hip/hip_runtime.h>

// DistNet: out[n] = sigmoid((min_p ||x_n - p||^2 + alpha) / beta)
// beta = softplus(beta_raw), alpha = -beta*ln(1000)
// x: [65536,128] f32, points: [2048,128] f32, beta_raw: [1] f32, out: [65536] f32
//
// R18: R17 (cooperative fusion) never executed under graph capture ->
// reverted to R14 (wall 92.3, session best). Remaining model: wall = OH~60
// (fill 43 harness-fixed + prep + gaps) + m~32 (x-burst 10, loop 9.4 vs 7.8
// L2 floor, residual ~12). TLP/L1-sharing/x-dedup all measured null. Last
// zero-cost lever: VGPR headroom -- at ~120 VGPR the grid (512 blocks =
// 2 blocks/CU) caps occupancy, not registers, so +32 VGPR of deeper
// prefetch is FREE. R18 = R14 + depth-8 named-buffer pipeline (16
// outstanding dwordx4/wave, 2x; loop iters 15->7) + 8-tile B-prologue
// issued BEFORE __syncthreads (L2 latency hides under barrier + A
// readback). Steady loop stays #pragma unroll 1, branch-free (R9 lesson).
// Pre-commit: if null, declare structural roofline.

#define NROWS 65536
#define NPTS  2048
#define DIMS  128
#define LOG1000F 6.9077542789816375f

typedef __attribute__((ext_vector_type(8))) int i32x8;
typedef __attribute__((ext_vector_type(4))) float f32x4;

union AFrag { int d[8]; i32x8 v; };
union BFrag { uint4 u4[2]; i32x8 v; };

// --- pre-kernel: points f32 -> fp8 e4m3, PRE-SWIZZLED fragment order --------
// 16B unit u = (T*2+c)*64 + q*16 + m  holds point p = T*16+m, features
// k in [q*32+c*16, q*32+c*16+16). Main kernel B-load for tile T is then
// unit[(T*2+c)*64 + lane], i.e. two contiguous 1KB dwordx4 loads.
// Also writes ||p||^2.
__global__ __launch_bounds__(256) void prep_points_kernel(
    const float* __restrict__ pts, unsigned char* __restrict__ ptsf8,
    float* __restrict__ pnorm)
{
    int tid  = threadIdx.x;
    int lane = tid & 63;
    int w    = tid >> 6;
    int pt   = blockIdx.x * 4 + w;            // one wave per point
    const float2 v = *reinterpret_cast<const float2*>(
        pts + (size_t)pt * DIMS + lane * 2);  // features 2*lane, 2*lane+1
    int pk = __builtin_amdgcn_cvt_pk_fp8_f32(v.x, v.y, 0, false);
    int T  = pt >> 4, pm = pt & 15;
    int q  = lane >> 4;                       // (2*lane)>>5
    int c  = (lane >> 3) & 1;                 // ((2*lane)>>4)&1
    int j  = (lane & 7) * 2;                  // (2*lane)&15
    size_t dst = (size_t)((T * 2 + c) * 64 + q * 16 + pm) * 16 + j;
    *reinterpret_cast<unsigned short*>(ptsf8 + dst) =
        (unsigned short)(pk & 0xFFFF);
    float ss = v.x * v.x + v.y * v.y;
    ss += __shfl_xor(ss, 1, 64);
    ss += __shfl_xor(ss, 2, 64);
    ss += __shfl_xor(ss, 4, 64);
    ss += __shfl_xor(ss, 8, 64);
    ss += __shfl_xor(ss, 16, 64);
    ss += __shfl_xor(ss, 32, 64);
    if (lane == 0) pnorm[pt] = ss;
}

// --- main kernel ------------------------------------------------------------
// grid: NROWS/128 = 512 blocks x 256 threads (4 waves, 2 per CU).
// Preamble: wave w converts row-tiles {2w, 2w+1} (x read exactly once),
// publishes fragments via LDS. Main loop: wave pair (pairw) owns 64 rows;
// half=0 wave does point-tiles 0..63, half=1 does 64..127. No barriers in
// the main loop.
__global__ __launch_bounds__(256, 2) void distnet_main_kernel(
    const float* __restrict__ x, const unsigned char* __restrict__ ptsf8,
    const float* __restrict__ pnorm, const float* __restrict__ beta_raw,
    float* __restrict__ out)
{
    __shared__ __align__(16) float s_pn[NPTS];   // 8 KB: -0.5*||p||^2
    __shared__ __align__(16) int s_af[8][64][8]; // 16 KB: A-frags, 8 row-tiles
    __shared__ float s_red[2][128];              // per-half partial max
    __shared__ float s_xn[128];                  // ||x||^2 per block row

    int tid = threadIdx.x;
    // stage -0.5*||p||^2 (MFMA C-input form) into LDS
    {
        const float4* p4 = reinterpret_cast<const float4*>(pnorm);
        float4* d4 = reinterpret_cast<float4*>(s_pn);
        float4 a = p4[tid], b = p4[tid + 256];
        d4[tid]       = make_float4(-.5f*a.x, -.5f*a.y, -.5f*a.z, -.5f*a.w);
        d4[tid + 256] = make_float4(-.5f*b.x, -.5f*b.y, -.5f*b.z, -.5f*b.w);
    }

    int wid   = tid >> 6, lane = tid & 63;
    int m     = lane & 15, q = lane >> 4;
    int pairw = wid >> 1, half = wid & 1;
    int rbase0 = blockIdx.x * 128;

    // Preamble: wave wid converts row-tiles {2*wid, 2*wid+1} only (x 1x).
    // Lane holds A[m][q*32+j] of each tile; publish to LDS for all waves.
#pragma unroll
    for (int i = 0; i < 2; ++i) {
        int lt = wid * 2 + i;                       // row-tile 0..7 in block
        const float* xp = x + (size_t)(rbase0 + lt * 16 + m) * DIMS + q * 32;
        AFrag af;
        float s = 0.f;
#pragma unroll
        for (int d = 0; d < 8; ++d) {
            float4 v = *reinterpret_cast<const float4*>(xp + d * 4);
            int w0 = __builtin_amdgcn_cvt_pk_fp8_f32(v.x, v.y, 0, false);
            w0 = __builtin_amdgcn_cvt_pk_fp8_f32(v.z, v.w, w0, true);
            af.d[d] = w0;
            s += v.x * v.x + v.y * v.y + v.z * v.z + v.w * v.w;
        }
        s += __shfl_xor(s, 16, 64);
        s += __shfl_xor(s, 32, 64);
        if (q == 0) s_xn[lt * 16 + m] = s;          // rows lt*16 + 0..15
        *reinterpret_cast<i32x8*>(&s_af[lt][lane][0]) = af.v;
    }

    // B prologue: issue 8 tile loads BEFORE the barrier (ptsf8 is ready --
    // prep ran in a prior dispatch; these L2 loads complete under the
    // barrier wait + A-fragment readback).
    const uint4* bsw = reinterpret_cast<const uint4*>(ptsf8);
    const int T0 = half * 64;      // this wave's 64-tile half of the points

    BFrag b0, b1, b2, b3, b4, b5, b6, b7;
    float pn0, pn1, pn2, pn3, pn4, pn5, pn6, pn7;

#define BLOAD(gT, buf) do {                            \
        buf.u4[0] = bsw[(gT) * 128 + lane];            \
        buf.u4[1] = bsw[(gT) * 128 + 64 + lane];       \
    } while (0)
#define LOADT(gT, buf, pnh) do {                       \
        BLOAD(gT, buf);                                \
        pnh = s_pn[(gT) * 16 + m];                     \
    } while (0)

    BLOAD(T0 + 0, b0);
    BLOAD(T0 + 1, b1);
    BLOAD(T0 + 2, b2);
    BLOAD(T0 + 3, b3);
    BLOAD(T0 + 4, b4);
    BLOAD(T0 + 5, b5);
    BLOAD(T0 + 6, b6);
    BLOAD(T0 + 7, b7);

    __syncthreads();   // s_pn + s_xn + s_af visible; only barrier before epi

    // Read back this wave's 4 row-tiles (pair's 64 rows) from LDS.
    AFrag afrag[4];
#pragma unroll
    for (int t = 0; t < 4; ++t)
        afrag[t].v = *reinterpret_cast<const i32x8*>(&s_af[pairw * 4 + t][lane][0]);

    pn0 = s_pn[(T0 + 0) * 16 + m];
    pn1 = s_pn[(T0 + 1) * 16 + m];
    pn2 = s_pn[(T0 + 2) * 16 + m];
    pn3 = s_pn[(T0 + 3) * 16 + m];
    pn4 = s_pn[(T0 + 4) * 16 + m];
    pn5 = s_pn[(T0 + 5) * 16 + m];
    pn6 = s_pn[(T0 + 6) * 16 + m];
    pn7 = s_pn[(T0 + 7) * 16 + m];

    // runmax tracks max_p (x.p - ||p||^2/2); d2 = ||x||^2 - 2*max at the end.
    float runmax[4][4];
#pragma unroll
    for (int t = 0; t < 4; ++t)
#pragma unroll
        for (int r = 0; r < 4; ++r) runmax[t][r] = -1e30f;

    auto compute = [&](const BFrag& buf, float pnh) {
#pragma unroll
        for (int t = 0; t < 4; ++t) {
            f32x4 acc = {pnh, pnh, pnh, pnh};   // C = -||p||^2/2 broadcast
            acc = __builtin_amdgcn_mfma_scale_f32_16x16x128_f8f6f4(
                afrag[t].v, buf.v, acc, 0, 0, 0, 0x7F7F7F7F, 0, 0x7F7F7F7F);
#pragma unroll
            for (int r = 0; r < 4; ++r)
                runmax[t][r] = fmaxf(runmax[t][r], acc[r]);
        }
    };

    // depth-8 register pipeline; steady loop branch-free and NOT unrolled
    // (R9 lesson: full unroll -> live-range blowup -> spill). 16 outstanding
    // dwordx4/wave; 7 iterations cover tiles 8..63.
#pragma unroll 1
    for (int T = 0; T < 56; T += 8) {
        compute(b0, pn0);
        LOADT(T0 + T +  8, b0, pn0);
        compute(b1, pn1);
        LOADT(T0 + T +  9, b1, pn1);
        compute(b2, pn2);
        LOADT(T0 + T + 10, b2, pn2);
        compute(b3, pn3);
        LOADT(T0 + T + 11, b3, pn3);
        compute(b4, pn4);
        LOADT(T0 + T + 12, b4, pn4);
        compute(b5, pn5);
        LOADT(T0 + T + 13, b5, pn5);
        compute(b6, pn6);
        LOADT(T0 + T + 14, b6, pn6);
        compute(b7, pn7);
        LOADT(T0 + T + 15, b7, pn7);
    }
    compute(b0, pn0);
    compute(b1, pn1);
    compute(b2, pn2);
    compute(b3, pn3);
    compute(b4, pn4);
    compute(b5, pn5);
    compute(b6, pn6);
    compute(b7, pn7);
#undef LOADT
#undef BLOAD

    // C/D layout: col = m (point), row_local = q*4 + r (x-row).
    // Max-reduce over the 16 cols, store per-half partial to LDS.
#pragma unroll
    for (int t = 0; t < 4; ++t) {
#pragma unroll
        for (int r = 0; r < 4; ++r) {
            float v = runmax[t][r];
            v = fmaxf(v, __shfl_xor(v, 1, 64));
            v = fmaxf(v, __shfl_xor(v, 2, 64));
            v = fmaxf(v, __shfl_xor(v, 4, 64));
            v = fmaxf(v, __shfl_xor(v, 8, 64));
            if (m == 0)
                s_red[half][pairw * 64 + t * 16 + q * 4 + r] = v;
        }
    }
    __syncthreads();

    if (tid < 128) {
        float vmax  = fmaxf(s_red[0][tid], s_red[1][tid]);
        float d2    = fmaxf(fmaf(-2.f, vmax, s_xn[tid]), 0.f);
        float br    = beta_raw[0];
        float beta  = log1pf(expf(br));
        float alpha = -beta * LOG1000F;
        float z     = (d2 + alpha) / beta;
        out[(size_t)blockIdx.x * 128 + tid] = 1.f / (1.f + expf(-z));
    }
}

extern "C" void kernel_launch(void* const* d_in, const int* in_sizes, int n_in,
                              void* d_out, int out_size, void* d_ws, size_t ws_size,
                              hipStream_t stream) {
    const float* x        = (const float*)d_in[0];
    const float* pts      = (const float*)d_in[1];
    const float* beta_raw = (const float*)d_in[2];
    float* out            = (float*)d_out;

    unsigned char* ptsf8 = (unsigned char*)d_ws;                    // 256 KB
    float* pnorm = (float*)((char*)d_ws + (size_t)NPTS * DIMS);     // 8 KB

    prep_points_kernel<<<NPTS / 4, 256, 0, stream>>>(pts, ptsf8, pnorm);
    distnet_main_kernel<<<NROWS / 128, 256, 0, stream>>>(x, ptsf8, pnorm,
                                                         beta_raw, out);
}